// Round 21
// baseline (1179.714 us; speedup 1.0000x reference)
//
#include <hip/hip_runtime.h>
#include <hip/hip_bf16.h>

#define DD 128
#define LW 136

typedef __attribute__((ext_vector_type(8))) short bf16x8;
typedef __attribute__((ext_vector_type(4))) float f32x4;

// split 8 fp32 -> packed bf16 hi (truncate) and lo (truncate of residual)
__device__ __forceinline__ void cvt8(const float4 a0, const float4 a1,
                                     bf16x8& hi, bf16x8& lo)
{
    float af[8] = {a0.x, a0.y, a0.z, a0.w, a1.x, a1.y, a1.z, a1.w};
    union { unsigned int u[4]; bf16x8 v; } H, L;
    #pragma unroll
    for (int i = 0; i < 4; ++i) {
        unsigned int b0 = __float_as_uint(af[2*i]);
        unsigned int b1 = __float_as_uint(af[2*i+1]);
        unsigned int h0 = b0 & 0xFFFF0000u;
        unsigned int h1 = b1 & 0xFFFF0000u;
        H.u[i] = (h0 >> 16) | h1;
        float r0 = af[2*i]   - __uint_as_float(h0);
        float r1 = af[2*i+1] - __uint_as_float(h1);
        L.u[i] = (__float_as_uint(r0) >> 16) | (__float_as_uint(r1) & 0xFFFF0000u);
    }
    hi = H.v; lo = L.v;
}

// fast sigmoid: 1/(1+exp(-z)) via v_rcp_f32 (~1ulp)
__device__ __forceinline__ float fsig(float z)
{
    return __builtin_amdgcn_rcpf(1.f + __expf(-z));
}

// ---------------- fused-MLP building blocks: 64-row tile, 4 waves x 32 cols --------
__device__ __forceinline__ void mfma_step(
    const unsigned short* __restrict__ WH, const unsigned short* __restrict__ WL,
    int wavecol, int l15, int kb,
    const bf16x8 ah[4], const bf16x8 al[4], f32x4 acc[4][2])
{
    bf16x8 bh[2], bl[2];
    #pragma unroll
    for (int ni = 0; ni < 2; ++ni) {
        int m = wavecol + ni * 16 + l15;
        bh[ni] = *(const bf16x8*)(WH + (size_t)m * DD + kb);
        bl[ni] = *(const bf16x8*)(WL + (size_t)m * DD + kb);
    }
    #pragma unroll
    for (int mi = 0; mi < 4; ++mi)
        #pragma unroll
        for (int ni = 0; ni < 2; ++ni) {
            acc[mi][ni] = __builtin_amdgcn_mfma_f32_16x16x32_bf16(ah[mi], bh[ni], acc[mi][ni], 0, 0, 0);
            acc[mi][ni] = __builtin_amdgcn_mfma_f32_16x16x32_bf16(ah[mi], bl[ni], acc[mi][ni], 0, 0, 0);
            acc[mi][ni] = __builtin_amdgcn_mfma_f32_16x16x32_bf16(al[mi], bh[ni], acc[mi][ni], 0, 0, 0);
        }
}

__device__ __forceinline__ void glb_layer(
    const float* __restrict__ X, int ldX, const int arow[4],
    const unsigned short* __restrict__ WU,
    int wavecol, int l15, int kg, f32x4 acc[4][2])
{
    const unsigned short* WH = WU;
    const unsigned short* WL = WU + 16384;
    #pragma unroll
    for (int kc = 0; kc < 4; ++kc) {
        const int kb = kc * 32 + kg;
        bf16x8 ah[4], al[4];
        #pragma unroll
        for (int mi = 0; mi < 4; ++mi) {
            const float* p = X + (size_t)arow[mi] * ldX + kb;
            float4 a0 = *(const float4*)p;
            float4 a1 = *(const float4*)(p + 4);
            cvt8(a0, a1, ah[mi], al[mi]);
        }
        mfma_step(WH, WL, wavecol, l15, kb, ah, al, acc);
    }
}

__device__ __forceinline__ void lds_layer(
    const unsigned short (*AH)[LW], const unsigned short (*AL)[LW],
    const unsigned short* __restrict__ WU,
    int wavecol, int l15, int kg, f32x4 acc[4][2])
{
    const unsigned short* WH = WU;
    const unsigned short* WL = WU + 16384;
    #pragma unroll
    for (int kc = 0; kc < 4; ++kc) {
        const int kb = kc * 32 + kg;
        bf16x8 ah[4], al[4];
        #pragma unroll
        for (int mi = 0; mi < 4; ++mi) {
            ah[mi] = *(const bf16x8*)&AH[mi * 16 + l15][kb];
            al[mi] = *(const bf16x8*)&AL[mi * 16 + l15][kb];
        }
        mfma_step(WH, WL, wavecol, l15, kb, ah, al, acc);
    }
}

__device__ __forceinline__ void epi_lds(
    const f32x4 acc[4][2], unsigned short (*AH)[LW], unsigned short (*AL)[LW],
    const float* __restrict__ bias, int wavecol, int l15, int rg, int relu)
{
    #pragma unroll
    for (int ni = 0; ni < 2; ++ni) {
        const int col = wavecol + ni * 16 + l15;
        const float bv = bias[col];
        #pragma unroll
        for (int mi = 0; mi < 4; ++mi)
            #pragma unroll
            for (int r = 0; r < 4; ++r) {
                const int row = mi * 16 + rg + r;
                float v = acc[mi][ni][r] + bv;
                if (relu) v = fmaxf(v, 0.f);
                unsigned int u = __float_as_uint(v), h = u & 0xFFFF0000u;
                float res = v - __uint_as_float(h);
                AH[row][col] = (unsigned short)(h >> 16);
                AL[row][col] = (unsigned short)(__float_as_uint(res) >> 16);
            }
    }
}

// ---- fused emb + kqvs layer0: emb3 stays in LDS, then 4 units -> bfused ----
__global__ __launch_bounds__(256) void fused_emb3q(
    const float* __restrict__ G, const unsigned short* __restrict__ Wt,
    const float* __restrict__ embb, const float* __restrict__ biasCat,
    float* __restrict__ bfused, int N)
{
    __shared__ unsigned short AH[64][LW], AL[64][LW];
    const int lane = threadIdx.x & 63, wid = threadIdx.x >> 6;
    const int wavecol = wid * 32;
    const int l15 = lane & 15, kg = (lane >> 4) * 8, rg = (lane >> 4) * 4;
    const int row0 = blockIdx.x * 64;

    int arow[4];
    #pragma unroll
    for (int mi = 0; mi < 4; ++mi) {
        int r = row0 + mi * 16 + l15;
        arow[mi] = r < N ? r : N - 1;
    }

    f32x4 acc[4][2] = {};
    glb_layer(G, DD, arow, Wt, wavecol, l15, kg, acc);
    epi_lds(acc, AH, AL, embb, wavecol, l15, rg, 1);
    __syncthreads();

    #pragma unroll
    for (int mi = 0; mi < 4; ++mi)
        #pragma unroll
        for (int ni = 0; ni < 2; ++ni) acc[mi][ni] = (f32x4){0,0,0,0};
    lds_layer(AH, AL, Wt + 32768, wavecol, l15, kg, acc);
    __syncthreads();
    epi_lds(acc, AH, AL, embb + 128, wavecol, l15, rg, 1);
    __syncthreads();

    #pragma unroll
    for (int mi = 0; mi < 4; ++mi)
        #pragma unroll
        for (int ni = 0; ni < 2; ++ni) acc[mi][ni] = (f32x4){0,0,0,0};
    lds_layer(AH, AL, Wt + 65536, wavecol, l15, kg, acc);
    __syncthreads();
    epi_lds(acc, AH, AL, embb + 256, wavecol, l15, rg, 1);
    __syncthreads();

    // kqvs layer 0: 4 units from LDS-resident emb3 output
    for (int cb = 0; cb < 4; ++cb) {
        #pragma unroll
        for (int mi = 0; mi < 4; ++mi)
            #pragma unroll
            for (int ni = 0; ni < 2; ++ni) acc[mi][ni] = (f32x4){0,0,0,0};
        lds_layer(AH, AL, Wt + (size_t)(3 + cb) * 32768, wavecol, l15, kg, acc);
        #pragma unroll
        for (int ni = 0; ni < 2; ++ni) {
            const int gcol = cb * 128 + wavecol + ni * 16 + l15;
            const float bv = biasCat[gcol];
            #pragma unroll
            for (int mi = 0; mi < 4; ++mi)
                #pragma unroll
                for (int r = 0; r < 4; ++r) {
                    int row = row0 + mi * 16 + rg + r;
                    if (row < N)
                        bfused[(size_t)row * 512 + gcol] = acc[mi][ni][r] + bv;
                }
        }
    }
}

// ---- fused kqvs (layer 1): X = K-block of bfused (stride 512); rewrite own rows ----
__global__ __launch_bounds__(256) void fused_kqvs(
    float* __restrict__ bfused, const unsigned short* __restrict__ Wt,
    const float* __restrict__ biasCat, int N)
{
    __shared__ unsigned short AH[64][LW], AL[64][LW];
    const int tid = threadIdx.x;
    const int lane = tid & 63, wid = tid >> 6;
    const int wavecol = wid * 32;
    const int l15 = lane & 15, kg = (lane >> 4) * 8, rg = (lane >> 4) * 4;
    const int row0 = blockIdx.x * 64;

    // stage X (K-block) into LDS, split to bf16 hi/lo
    for (int idx = tid; idx < 64 * 128; idx += 256) {
        const int row = idx >> 7, col = idx & 127;
        int gr = row0 + row; if (gr >= N) gr = N - 1;
        float v = bfused[(size_t)gr * 512 + col];
        unsigned int u = __float_as_uint(v), h = u & 0xFFFF0000u;
        float res = v - __uint_as_float(h);
        AH[row][col] = (unsigned short)(h >> 16);
        AL[row][col] = (unsigned short)(__float_as_uint(res) >> 16);
    }
    __syncthreads();

    f32x4 acc[4][2];
    for (int cb = 0; cb < 4; ++cb) {
        #pragma unroll
        for (int mi = 0; mi < 4; ++mi)
            #pragma unroll
            for (int ni = 0; ni < 2; ++ni) acc[mi][ni] = (f32x4){0,0,0,0};
        lds_layer(AH, AL, Wt + (size_t)cb * 32768, wavecol, l15, kg, acc);
        #pragma unroll
        for (int ni = 0; ni < 2; ++ni) {
            const int gcol = cb * 128 + wavecol + ni * 16 + l15;
            const float bv = biasCat[gcol];
            #pragma unroll
            for (int mi = 0; mi < 4; ++mi)
                #pragma unroll
                for (int r = 0; r < 4; ++r) {
                    int row = row0 + mi * 16 + rg + r;
                    if (row < N)
                        bfused[(size_t)row * 512 + gcol] = acc[mi][ni][r] + bv;
                }
        }
    }
}

// ---- fused g1,g2 + colsum: in = K-block, out = Q-block of bfused ----
__global__ __launch_bounds__(256) void fused_g12(
    float* __restrict__ bfused, const unsigned short* __restrict__ Wt,
    const float* __restrict__ g1b, const float* __restrict__ g2b,
    float* __restrict__ gsum, int N)
{
    __shared__ unsigned short AH[64][LW], AL[64][LW];
    __shared__ float csum[128];
    const int tid = threadIdx.x;
    const int lane = tid & 63, wid = tid >> 6;
    const int wavecol = wid * 32;
    const int l15 = lane & 15, kg = (lane >> 4) * 8, rg = (lane >> 4) * 4;
    const int row0 = blockIdx.x * 64;

    if (tid < 128) csum[tid] = 0.f;

    int arow[4];
    #pragma unroll
    for (int mi = 0; mi < 4; ++mi) {
        int r = row0 + mi * 16 + l15;
        arow[mi] = r < N ? r : N - 1;
    }

    f32x4 acc[4][2] = {};
    glb_layer(bfused, 512, arow, Wt, wavecol, l15, kg, acc);
    epi_lds(acc, AH, AL, g1b, wavecol, l15, rg, 1);
    __syncthreads();

    #pragma unroll
    for (int mi = 0; mi < 4; ++mi)
        #pragma unroll
        for (int ni = 0; ni < 2; ++ni) acc[mi][ni] = (f32x4){0,0,0,0};
    lds_layer(AH, AL, Wt + 32768, wavecol, l15, kg, acc);

    #pragma unroll
    for (int ni = 0; ni < 2; ++ni) {
        const int col = wavecol + ni * 16 + l15;
        const float bv = g2b[col];
        float part = 0.f;
        #pragma unroll
        for (int mi = 0; mi < 4; ++mi)
            #pragma unroll
            for (int r = 0; r < 4; ++r) {
                int row = row0 + mi * 16 + rg + r;
                if (row < N) {
                    float v = acc[mi][ni][r] + bv;
                    bfused[(size_t)row * 512 + 128 + col] = v;   // Q-block scratch
                    part += v;
                }
            }
        atomicAdd(&csum[col], part);
    }
    __syncthreads();
    if (tid < 128) atomicAdd(&gsum[tid], csum[tid]);
}

// ---- fused head: in = Q-block of bfused ----
__global__ __launch_bounds__(256) void fused_head(
    const float* __restrict__ bfused, const unsigned short* __restrict__ Wt,
    const float* __restrict__ cvec, const float* __restrict__ h2b,
    const float* __restrict__ h3w, const float* __restrict__ h3b,
    float* __restrict__ out, int N)
{
    __shared__ unsigned short AH[64][LW], AL[64][LW];
    const int tid = threadIdx.x;
    const int lane = tid & 63, wid = tid >> 6;
    const int wavecol = wid * 32;
    const int l15 = lane & 15, kg = (lane >> 4) * 8, rg = (lane >> 4) * 4;
    const int row0 = blockIdx.x * 64;

    int arow[4];
    #pragma unroll
    for (int mi = 0; mi < 4; ++mi) {
        int r = row0 + mi * 16 + l15;
        arow[mi] = r < N ? r : N - 1;
    }

    f32x4 acc[4][2] = {};
    glb_layer(bfused + 128, 512, arow, Wt, wavecol, l15, kg, acc);
    epi_lds(acc, AH, AL, cvec, wavecol, l15, rg, 1);
    __syncthreads();

    #pragma unroll
    for (int mi = 0; mi < 4; ++mi)
        #pragma unroll
        for (int ni = 0; ni < 2; ++ni) acc[mi][ni] = (f32x4){0,0,0,0};
    lds_layer(AH, AL, Wt + 32768, wavecol, l15, kg, acc);
    __syncthreads();
    epi_lds(acc, AH, AL, h2b, wavecol, l15, rg, 1);
    __syncthreads();

    const int row = tid >> 2, seg = tid & 3;
    float s = 0.f;
    #pragma unroll 8
    for (int j = 0; j < 32; ++j) {
        int col = seg * 32 + j;
        float xv = __uint_as_float((unsigned int)AH[row][col] << 16)
                 + __uint_as_float((unsigned int)AL[row][col] << 16);
        s = fmaf(xv, h3w[col], s);
    }
    s += __shfl_xor(s, 1, 64);
    s += __shfl_xor(s, 2, 64);
    if (seg == 0 && row0 + row < N) out[row0 + row] = s + h3b[0];
}

// one-time: transpose+split weight units to bf16 hi/lo [m][k].
__global__ __launch_bounds__(256) void prep_weights(
    const float* __restrict__ embW, const float* __restrict__ keyW,
    const float* __restrict__ qryW, const float* __restrict__ valW,
    const float* __restrict__ skpW, const float* __restrict__ g1W,
    const float* __restrict__ g2W, const float* __restrict__ h1W,
    const float* __restrict__ h2W,
    const float* __restrict__ keyb, const float* __restrict__ qryb,
    const float* __restrict__ valb, const float* __restrict__ skpb,
    unsigned short* __restrict__ Wt, float* __restrict__ biasCat)
{
    const int u = blockIdx.x;   // 0..14
    const int t = threadIdx.x;
    __shared__ float T[128][129];

    const float* src;
    if (u < 3)       src = embW + (size_t)u * 16384;
    else if (u < 7)  { const float* p[4] = {keyW, qryW, valW, skpW}; src = p[u - 3]; }
    else if (u < 11) { const float* p[4] = {keyW, qryW, valW, skpW}; src = p[u - 7] + 16384; }
    else if (u == 11) src = g1W;
    else if (u == 12) src = g2W;
    else if (u == 13) src = h1W;
    else              src = h2W;

    #pragma unroll
    for (int i = 0; i < 64; ++i) {
        int idx = t + 256 * i;
        T[idx >> 7][idx & 127] = src[idx];
    }
    __syncthreads();

    unsigned short* dH = Wt + (size_t)u * 32768;
    unsigned short* dL = dH + 16384;
    const int m = t >> 1, kbase = (t & 1) * 64;
    for (int j = 0; j < 64; ++j) {
        int k = kbase + j;
        float a = T[k][m];
        unsigned int b = __float_as_uint(a);
        unsigned int h = b & 0xFFFF0000u;
        float r = a - __uint_as_float(h);
        dH[m * 128 + k] = (unsigned short)(h >> 16);
        dL[m * 128 + k] = (unsigned short)(__float_as_uint(r) >> 16);
    }

    if (u == 0) {
        for (int x = t; x < 1024; x += 256) {
            int L = x >> 9, c = x & 511;
            const float* bp = (c < 128) ? keyb : (c < 256) ? qryb : (c < 384) ? valb : skpb;
            biasCat[x] = bp[L * 128 + (c & 127)];
        }
    }
}

// ---------------- CSR build ----------------
__global__ void hist_kernel(const int* __restrict__ dstA, int* __restrict__ hist, int E)
{
    for (int e = blockIdx.x * blockDim.x + threadIdx.x; e < E;
         e += gridDim.x * blockDim.x)
        atomicAdd(&hist[dstA[e]], 1);
}

__global__ __launch_bounds__(256) void scan1_kernel(
    const int* __restrict__ in, int n_in,
    int* __restrict__ out, int* __restrict__ bsum, int n)
{
    __shared__ int wtot[4];
    const int t = threadIdx.x, lane = t & 63, wv = t >> 6;
    const int base = blockIdx.x * 1024 + t * 4;
    int v[4]; int sum = 0;
    #pragma unroll
    for (int j = 0; j < 4; ++j) {
        int idx = base + j;
        v[j] = (idx < n_in) ? in[idx] : 0;
        sum += v[j];
    }
    int incl = sum;
    #pragma unroll
    for (int d = 1; d < 64; d <<= 1) {
        int y = __shfl_up(incl, d, 64);
        if (lane >= d) incl += y;
    }
    if (lane == 63) wtot[wv] = incl;
    __syncthreads();
    int woff = 0;
    for (int w = 0; w < wv; ++w) woff += wtot[w];
    int run = woff + incl - sum;
    #pragma unroll
    for (int j = 0; j < 4; ++j) {
        int idx = base + j;
        if (idx < n) out[idx] = run;
        run += v[j];
    }
    if (t == 0)
        bsum[blockIdx.x] = wtot[0] + wtot[1] + wtot[2] + wtot[3];
}

__global__ void scan2_kernel(int* __restrict__ bsum, int nb)
{
    if (blockIdx.x == 0 && threadIdx.x == 0) {
        int run = 0;
        for (int i = 0; i < nb; ++i) { int t = bsum[i]; bsum[i] = run; run += t; }
    }
}

__global__ __launch_bounds__(256) void scan3_kernel(
    int* __restrict__ out, const int* __restrict__ bsum,
    int* __restrict__ cursor, int n, int n_nodes)
{
    const int base = blockIdx.x * 1024 + threadIdx.x * 4;
    const int add = bsum[blockIdx.x];
    #pragma unroll
    for (int j = 0; j < 4; ++j) {
        int idx = base + j;
        if (idx < n) {
            int vv = out[idx] + add;
            out[idx] = vv;
            if (idx < n_nodes) cursor[idx] = vv;
        }
    }
}

// fused scatter: srcp[pos] = src; eaP[pos] = ea[e] (dst-sorted, stride 24)
__global__ void scatter_ea(const int* __restrict__ srcA, const int* __restrict__ dstA,
                           const float* __restrict__ ea, int* __restrict__ cursor,
                           int* __restrict__ srcp, float* __restrict__ eaP, int E)
{
    for (int e = blockIdx.x * blockDim.x + threadIdx.x; e < E;
         e += gridDim.x * blockDim.x) {
        int d = dstA[e];
        int pos = atomicAdd(&cursor[d], 1);
        srcp[pos] = srcA[e];
        const float* s = ea + (size_t)e * 21;
        float* q = eaP + (size_t)pos * 24;
        #pragma unroll
        for (int j = 0; j < 21; ++j) q[j] = s[j];
    }
}

// ---------------- edge aggregation: wave handles 2 independent dsts (dual-stream ILP)
// fused row: [K | Q | V | Sk]; output written into K-block (cols 0..127).
__global__ __launch_bounds__(256) void edge_agg17(
    const int* __restrict__ row_ptr, const int* __restrict__ srcp,
    const float* __restrict__ eaP,
    const float* __restrict__ We, const float* __restrict__ be,
    float* __restrict__ fused, int N)
{
    const int wv = threadIdx.x >> 6, lane = threadIdx.x & 63;
    const int d0 = blockIdx.x * 8 + wv * 2;
    const int d1 = d0 + 1;
    if (d0 >= N) return;
    const bool has1 = d1 < N;
    const int c = lane * 2;

    float2 w[21];
    #pragma unroll
    for (int j = 0; j < 21; ++j)
        w[j] = *(const float2*)(We + j * DD + c);
    const float2 b2 = *(const float2*)(be + c);

    const float2 kd0 = *(const float2*)(fused + (size_t)d0 * 512 + c);
    const float2 sk0 = *(const float2*)(fused + (size_t)d0 * 512 + 384 + c);
    const float2 kd1 = has1 ? *(const float2*)(fused + (size_t)d1 * 512 + c) : kd0;
    const float2 sk1 = has1 ? *(const float2*)(fused + (size_t)d1 * 512 + 384 + c) : sk0;

    const int a0 = __builtin_amdgcn_readfirstlane(row_ptr[d0]);
    const int a1 = __builtin_amdgcn_readfirstlane(row_ptr[d0 + 1]);
    const int b0 = has1 ? __builtin_amdgcn_readfirstlane(row_ptr[d1]) : 0;
    const int b1 = has1 ? __builtin_amdgcn_readfirstlane(row_ptr[d1 + 1]) : 0;
    const int na = a1 - a0;
    const int nb2 = b1 - b0;
    const int nmax = na > nb2 ? na : nb2;

    float ax0 = 0.f, ay0 = 0.f, ax1 = 0.f, ay1 = 0.f;

    for (int t = 0; t < nmax; ++t) {
        // stream A: one edge of d0 (clamped + weight)
        const int ta = t < na ? t : (na - 1);
        const float wA = (t < na) ? 1.f : 0.f;
        const int iA = a0 + (ta < 0 ? 0 : ta);
        // stream B: one edge of d1
        const int tb = t < nb2 ? t : (nb2 - 1);
        const float wB = (has1 && t < nb2) ? 1.f : 0.f;
        const int iB = b0 + (tb < 0 ? 0 : tb);

        const int sA = __builtin_amdgcn_readfirstlane(srcp[iA]);
        const int sB = __builtin_amdgcn_readfirstlane(srcp[iB]);

        const float* eA = eaP + (size_t)iA * 24;
        const float* eB = eaP + (size_t)iB * 24;
        float aA[21], aB[21];
        #pragma unroll
        for (int j = 0; j < 21; ++j) { aA[j] = eA[j]; aB[j] = eB[j]; }

        const float* fpA = fused + (size_t)sA * 512;
        const float* fpB = fused + (size_t)sB * 512;
        float2 qA = *(const float2*)(fpA + 128 + c);
        float2 vA = *(const float2*)(fpA + 256 + c);
        float2 qB = *(const float2*)(fpB + 128 + c);
        float2 vB = *(const float2*)(fpB + 256 + c);

        float pxA[4] = {0,0,0,0}, pyA[4] = {0,0,0,0};
        float pxB[4] = {0,0,0,0}, pyB[4] = {0,0,0,0};
        #pragma unroll
        for (int j = 0; j < 21; ++j) {
            int s = j & 3;
            pxA[s] = fmaf(aA[j], w[j].x, pxA[s]);
            pyA[s] = fmaf(aA[j], w[j].y, pyA[s]);
            pxB[s] = fmaf(aB[j], w[j].x, pxB[s]);
            pyB[s] = fmaf(aB[j], w[j].y, pyB[s]);
        }
        float exA = (pxA[0] + pxA[1]) + (pxA[2] + pxA[3]) + b2.x;
        float eyA = (pyA[0] + pyA[1]) + (pyA[2] + pyA[3]) + b2.y;
        float exB = (pxB[0] + pxB[1]) + (pxB[2] + pxB[3]) + b2.x;
        float eyB = (pyB[0] + pyB[1]) + (pyB[2] + pyB[3]) + b2.y;

        float gxA = wA * fsig(kd0.x + qA.x + exA);
        float gyA = wA * fsig(kd0.y + qA.y + eyA);
        float gxB = wB * fsig(kd1.x + qB.x + exB);
        float gyB = wB * fsig(kd1.y + qB.y + eyB);

        ax0 = fmaf(gxA, vA.x, ax0);
        ay0 = fmaf(gyA, vA.y, ay0);
        ax1 = fmaf(gxB, vB.x, ax1);
        ay1 = fmaf(gyB, vB.y, ay1);
    }

    float* xr0 = fused + (size_t)d0 * 512;
    xr0[c]     = fmaxf(ax0 + sk0.x, 0.f);
    xr0[c + 1] = fmaxf(ay0 + sk0.y, 0.f);
    if (has1) {
        float* xr1 = fused + (size_t)d1 * 512;
        xr1[c]     = fmaxf(ax1 + sk1.x, 0.f);
        xr1[c + 1] = fmaxf(ay1 + sk1.y, 0.f);
    }
}

__global__ void cvec_kernel(const float* __restrict__ gsum, const float* __restrict__ h1W,
                            const float* __restrict__ h1b, float* __restrict__ cvec, float invN)
{
    const int m = threadIdx.x;
    float acc = h1b[m];
    for (int k = 0; k < 128; ++k)
        acc = fmaf(gsum[k] * invN, h1W[(size_t)(128 + k) * DD + m], acc);
    cvec[m] = acc;
}

extern "C" void kernel_launch(void* const* d_in, const int* in_sizes, int n_in,
                              void* d_out, int out_size, void* d_ws, size_t ws_size,
                              hipStream_t stream)
{
    const float* G    = (const float*)d_in[0];
    const int*   ei   = (const int*)  d_in[1];
    const float* ea   = (const float*)d_in[2];
    const float* embW = (const float*)d_in[3];
    const float* embb = (const float*)d_in[4];
    const float* keyW = (const float*)d_in[5];
    const float* keyb = (const float*)d_in[6];
    const float* qryW = (const float*)d_in[7];
    const float* qryb = (const float*)d_in[8];
    const float* valW = (const float*)d_in[9];
    const float* valb = (const float*)d_in[10];
    const float* skpW = (const float*)d_in[11];
    const float* skpb = (const float*)d_in[12];
    const float* edgW = (const float*)d_in[13];
    const float* edgb = (const float*)d_in[14];
    const float* g1W  = (const float*)d_in[15];
    const float* g1b  = (const float*)d_in[16];
    const float* g2W  = (const float*)d_in[17];
    const float* g2b  = (const float*)d_in[18];
    const float* h1W  = (const float*)d_in[19];
    const float* h1b  = (const float*)d_in[20];
    const float* h2W  = (const float*)d_in[21];
    const float* h2b  = (const float*)d_in[22];
    const float* h3W  = (const float*)d_in[23];
    const float* h3b  = (const float*)d_in[24];

    const int N = in_sizes[0] / DD;    // 100000
    const int E = in_sizes[2] / 21;    // 1000000
    const int* srcA = ei;
    const int* dstA = ei + E;

    float* bfused = (float*)d_ws;                        // [N][512]
    float* gsum   = bfused + (size_t)N * 512;            // 128
    float* cvec   = gsum + DD;                           // 128
    float* biasCat= cvec + DD;                           // 1024
    unsigned short* Wt = (unsigned short*)(biasCat + 1024);  // 15*32768 ushorts
    int* hist = (int*)((char*)Wt + (size_t)15 * 32768 * 2);  // N
    int* row  = hist + N;              // N+1
    int* cur  = row + N + 1;           // N
    int* bsum = cur + N;               // 128
    int* srcp = bsum + 128;            // E
    float* eaP = (float*)(srcp + E);   // E*24

    const int fgrid   = (N + 63) / 64;
    const int aggGrid = (N + 7) / 8;
    const int nScan = N + 1;
    const int nb = (nScan + 1023) / 1024;

    // ---- weight prep + CSR build (scatter fused with ea permute) ----
    prep_weights<<<15, 256, 0, stream>>>(embW, keyW, qryW, valW, skpW,
                                         g1W, g2W, h1W, h2W,
                                         keyb, qryb, valb, skpb, Wt, biasCat);
    hipMemsetAsync(hist, 0, (size_t)N * sizeof(int), stream);
    hipMemsetAsync(gsum, 0, DD * sizeof(float), stream);
    hist_kernel<<<1024, 256, 0, stream>>>(dstA, hist, E);
    scan1_kernel<<<nb, 256, 0, stream>>>(hist, N, row, bsum, nScan);
    scan2_kernel<<<1, 64, 0, stream>>>(bsum, nb);
    scan3_kernel<<<nb, 256, 0, stream>>>(row, bsum, cur, nScan, N);
    scatter_ea<<<1024, 256, 0, stream>>>(srcA, dstA, ea, cur, srcp, eaP, E);

    #define UNIT(u) (Wt + (size_t)(u) * 32768)

    // ---- emb MLP + kqvs layer0 fused: G -> bfused ----
    fused_emb3q<<<fgrid, 256, 0, stream>>>(G, Wt, embb, biasCat, bfused, N);

    // ---- conv layer 0 edges: bfused -> K-block of bfused ----
    edge_agg17<<<aggGrid, 256, 0, stream>>>(row, srcp, eaP,
                                            edgW + 0, edgb + 0, bfused, N);

    // ---- conv layer 1: kqvs (K-block in, full rows out); edges -> K-block ----
    fused_kqvs<<<fgrid, 256, 0, stream>>>(bfused, UNIT(7), biasCat + 512, N);
    edge_agg17<<<aggGrid, 256, 0, stream>>>(row, srcp, eaP,
                                            edgW + 21*DD, edgb + DD, bfused, N);

    // ---- g1+g2+colsum fused: K-block -> Q-block, gsum ----
    fused_g12<<<fgrid, 256, 0, stream>>>(bfused, UNIT(11), g1b, g2b, gsum, N);

    // ---- cvec = h1b + (gmean @ h1W[D:]) ----
    cvec_kernel<<<1, DD, 0, stream>>>(gsum, h1W, h1b, cvec, 1.0f / (float)N);

    // ---- head fused: Q-block -> out ----
    fused_head<<<fgrid, 256, 0, stream>>>(bfused, UNIT(13), cvec, h2b, h3W, h3b,
                                          (float*)d_out, N);
}

// Round 22
// 1028.097 us; speedup vs baseline: 1.1475x; 1.1475x over previous
//
#include <hip/hip_runtime.h>
#include <hip/hip_bf16.h>

#define DD 128
#define LW 136

typedef __attribute__((ext_vector_type(8))) short bf16x8;
typedef __attribute__((ext_vector_type(4))) float f32x4;

// split 8 fp32 -> packed bf16 hi (truncate) and lo (truncate of residual)
__device__ __forceinline__ void cvt8(const float4 a0, const float4 a1,
                                     bf16x8& hi, bf16x8& lo)
{
    float af[8] = {a0.x, a0.y, a0.z, a0.w, a1.x, a1.y, a1.z, a1.w};
    union { unsigned int u[4]; bf16x8 v; } H, L;
    #pragma unroll
    for (int i = 0; i < 4; ++i) {
        unsigned int b0 = __float_as_uint(af[2*i]);
        unsigned int b1 = __float_as_uint(af[2*i+1]);
        unsigned int h0 = b0 & 0xFFFF0000u;
        unsigned int h1 = b1 & 0xFFFF0000u;
        H.u[i] = (h0 >> 16) | h1;
        float r0 = af[2*i]   - __uint_as_float(h0);
        float r1 = af[2*i+1] - __uint_as_float(h1);
        L.u[i] = (__float_as_uint(r0) >> 16) | (__float_as_uint(r1) & 0xFFFF0000u);
    }
    hi = H.v; lo = L.v;
}

// fast sigmoid: 1/(1+exp(-z)) via v_rcp_f32 (~1ulp)
__device__ __forceinline__ float fsig(float z)
{
    return __builtin_amdgcn_rcpf(1.f + __expf(-z));
}

// ---------------- fused-MLP building blocks: 64-row tile, 4 waves x 32 cols --------
__device__ __forceinline__ void mfma_step(
    const unsigned short* __restrict__ WH, const unsigned short* __restrict__ WL,
    int wavecol, int l15, int kb,
    const bf16x8 ah[4], const bf16x8 al[4], f32x4 acc[4][2])
{
    bf16x8 bh[2], bl[2];
    #pragma unroll
    for (int ni = 0; ni < 2; ++ni) {
        int m = wavecol + ni * 16 + l15;
        bh[ni] = *(const bf16x8*)(WH + (size_t)m * DD + kb);
        bl[ni] = *(const bf16x8*)(WL + (size_t)m * DD + kb);
    }
    #pragma unroll
    for (int mi = 0; mi < 4; ++mi)
        #pragma unroll
        for (int ni = 0; ni < 2; ++ni) {
            acc[mi][ni] = __builtin_amdgcn_mfma_f32_16x16x32_bf16(ah[mi], bh[ni], acc[mi][ni], 0, 0, 0);
            acc[mi][ni] = __builtin_amdgcn_mfma_f32_16x16x32_bf16(ah[mi], bl[ni], acc[mi][ni], 0, 0, 0);
            acc[mi][ni] = __builtin_amdgcn_mfma_f32_16x16x32_bf16(al[mi], bh[ni], acc[mi][ni], 0, 0, 0);
        }
}

__device__ __forceinline__ void glb_layer(
    const float* __restrict__ X, int ldX, const int arow[4],
    const unsigned short* __restrict__ WU,
    int wavecol, int l15, int kg, f32x4 acc[4][2])
{
    const unsigned short* WH = WU;
    const unsigned short* WL = WU + 16384;
    #pragma unroll
    for (int kc = 0; kc < 4; ++kc) {
        const int kb = kc * 32 + kg;
        bf16x8 ah[4], al[4];
        #pragma unroll
        for (int mi = 0; mi < 4; ++mi) {
            const float* p = X + (size_t)arow[mi] * ldX + kb;
            float4 a0 = *(const float4*)p;
            float4 a1 = *(const float4*)(p + 4);
            cvt8(a0, a1, ah[mi], al[mi]);
        }
        mfma_step(WH, WL, wavecol, l15, kb, ah, al, acc);
    }
}

__device__ __forceinline__ void lds_layer(
    const unsigned short (*AH)[LW], const unsigned short (*AL)[LW],
    const unsigned short* __restrict__ WU,
    int wavecol, int l15, int kg, f32x4 acc[4][2])
{
    const unsigned short* WH = WU;
    const unsigned short* WL = WU + 16384;
    #pragma unroll
    for (int kc = 0; kc < 4; ++kc) {
        const int kb = kc * 32 + kg;
        bf16x8 ah[4], al[4];
        #pragma unroll
        for (int mi = 0; mi < 4; ++mi) {
            ah[mi] = *(const bf16x8*)&AH[mi * 16 + l15][kb];
            al[mi] = *(const bf16x8*)&AL[mi * 16 + l15][kb];
        }
        mfma_step(WH, WL, wavecol, l15, kb, ah, al, acc);
    }
}

__device__ __forceinline__ void epi_lds(
    const f32x4 acc[4][2], unsigned short (*AH)[LW], unsigned short (*AL)[LW],
    const float* __restrict__ bias, int wavecol, int l15, int rg, int relu)
{
    #pragma unroll
    for (int ni = 0; ni < 2; ++ni) {
        const int col = wavecol + ni * 16 + l15;
        const float bv = bias[col];
        #pragma unroll
        for (int mi = 0; mi < 4; ++mi)
            #pragma unroll
            for (int r = 0; r < 4; ++r) {
                const int row = mi * 16 + rg + r;
                float v = acc[mi][ni][r] + bv;
                if (relu) v = fmaxf(v, 0.f);
                unsigned int u = __float_as_uint(v), h = u & 0xFFFF0000u;
                float res = v - __uint_as_float(h);
                AH[row][col] = (unsigned short)(h >> 16);
                AL[row][col] = (unsigned short)(__float_as_uint(res) >> 16);
            }
    }
}

// ---- fused emb + kqvs layer0: emb3 stays in LDS, then 4 units -> bfused ----
__global__ __launch_bounds__(256) void fused_emb3q(
    const float* __restrict__ G, const unsigned short* __restrict__ Wt,
    const float* __restrict__ embb, const float* __restrict__ biasCat,
    float* __restrict__ bfused, int N)
{
    __shared__ unsigned short AH[64][LW], AL[64][LW];
    const int lane = threadIdx.x & 63, wid = threadIdx.x >> 6;
    const int wavecol = wid * 32;
    const int l15 = lane & 15, kg = (lane >> 4) * 8, rg = (lane >> 4) * 4;
    const int row0 = blockIdx.x * 64;

    int arow[4];
    #pragma unroll
    for (int mi = 0; mi < 4; ++mi) {
        int r = row0 + mi * 16 + l15;
        arow[mi] = r < N ? r : N - 1;
    }

    f32x4 acc[4][2] = {};
    glb_layer(G, DD, arow, Wt, wavecol, l15, kg, acc);
    epi_lds(acc, AH, AL, embb, wavecol, l15, rg, 1);
    __syncthreads();

    #pragma unroll
    for (int mi = 0; mi < 4; ++mi)
        #pragma unroll
        for (int ni = 0; ni < 2; ++ni) acc[mi][ni] = (f32x4){0,0,0,0};
    lds_layer(AH, AL, Wt + 32768, wavecol, l15, kg, acc);
    __syncthreads();
    epi_lds(acc, AH, AL, embb + 128, wavecol, l15, rg, 1);
    __syncthreads();

    #pragma unroll
    for (int mi = 0; mi < 4; ++mi)
        #pragma unroll
        for (int ni = 0; ni < 2; ++ni) acc[mi][ni] = (f32x4){0,0,0,0};
    lds_layer(AH, AL, Wt + 65536, wavecol, l15, kg, acc);
    __syncthreads();
    epi_lds(acc, AH, AL, embb + 256, wavecol, l15, rg, 1);
    __syncthreads();

    // kqvs layer 0: 4 units from LDS-resident emb3 output
    for (int cb = 0; cb < 4; ++cb) {
        #pragma unroll
        for (int mi = 0; mi < 4; ++mi)
            #pragma unroll
            for (int ni = 0; ni < 2; ++ni) acc[mi][ni] = (f32x4){0,0,0,0};
        lds_layer(AH, AL, Wt + (size_t)(3 + cb) * 32768, wavecol, l15, kg, acc);
        #pragma unroll
        for (int ni = 0; ni < 2; ++ni) {
            const int gcol = cb * 128 + wavecol + ni * 16 + l15;
            const float bv = biasCat[gcol];
            #pragma unroll
            for (int mi = 0; mi < 4; ++mi)
                #pragma unroll
                for (int r = 0; r < 4; ++r) {
                    int row = row0 + mi * 16 + rg + r;
                    if (row < N)
                        bfused[(size_t)row * 512 + gcol] = acc[mi][ni][r] + bv;
                }
        }
    }
}

// ---- fused kqvs (layer 1): X = K-block of bfused (stride 512); rewrite own rows ----
__global__ __launch_bounds__(256) void fused_kqvs(
    float* __restrict__ bfused, const unsigned short* __restrict__ Wt,
    const float* __restrict__ biasCat, int N)
{
    __shared__ unsigned short AH[64][LW], AL[64][LW];
    const int tid = threadIdx.x;
    const int lane = tid & 63, wid = tid >> 6;
    const int wavecol = wid * 32;
    const int l15 = lane & 15, kg = (lane >> 4) * 8, rg = (lane >> 4) * 4;
    const int row0 = blockIdx.x * 64;

    // stage X (K-block) into LDS, split to bf16 hi/lo
    for (int idx = tid; idx < 64 * 128; idx += 256) {
        const int row = idx >> 7, col = idx & 127;
        int gr = row0 + row; if (gr >= N) gr = N - 1;
        float v = bfused[(size_t)gr * 512 + col];
        unsigned int u = __float_as_uint(v), h = u & 0xFFFF0000u;
        float res = v - __uint_as_float(h);
        AH[row][col] = (unsigned short)(h >> 16);
        AL[row][col] = (unsigned short)(__float_as_uint(res) >> 16);
    }
    __syncthreads();

    f32x4 acc[4][2];
    for (int cb = 0; cb < 4; ++cb) {
        #pragma unroll
        for (int mi = 0; mi < 4; ++mi)
            #pragma unroll
            for (int ni = 0; ni < 2; ++ni) acc[mi][ni] = (f32x4){0,0,0,0};
        lds_layer(AH, AL, Wt + (size_t)cb * 32768, wavecol, l15, kg, acc);
        #pragma unroll
        for (int ni = 0; ni < 2; ++ni) {
            const int gcol = cb * 128 + wavecol + ni * 16 + l15;
            const float bv = biasCat[gcol];
            #pragma unroll
            for (int mi = 0; mi < 4; ++mi)
                #pragma unroll
                for (int r = 0; r < 4; ++r) {
                    int row = row0 + mi * 16 + rg + r;
                    if (row < N)
                        bfused[(size_t)row * 512 + gcol] = acc[mi][ni][r] + bv;
                }
        }
    }
}

// ---- fused g1,g2 + colsum: in = K-block, out = Q-block of bfused ----
__global__ __launch_bounds__(256) void fused_g12(
    float* __restrict__ bfused, const unsigned short* __restrict__ Wt,
    const float* __restrict__ g1b, const float* __restrict__ g2b,
    float* __restrict__ gsum, int N)
{
    __shared__ unsigned short AH[64][LW], AL[64][LW];
    __shared__ float csum[128];
    const int tid = threadIdx.x;
    const int lane = tid & 63, wid = tid >> 6;
    const int wavecol = wid * 32;
    const int l15 = lane & 15, kg = (lane >> 4) * 8, rg = (lane >> 4) * 4;
    const int row0 = blockIdx.x * 64;

    if (tid < 128) csum[tid] = 0.f;

    int arow[4];
    #pragma unroll
    for (int mi = 0; mi < 4; ++mi) {
        int r = row0 + mi * 16 + l15;
        arow[mi] = r < N ? r : N - 1;
    }

    f32x4 acc[4][2] = {};
    glb_layer(bfused, 512, arow, Wt, wavecol, l15, kg, acc);
    epi_lds(acc, AH, AL, g1b, wavecol, l15, rg, 1);
    __syncthreads();

    #pragma unroll
    for (int mi = 0; mi < 4; ++mi)
        #pragma unroll
        for (int ni = 0; ni < 2; ++ni) acc[mi][ni] = (f32x4){0,0,0,0};
    lds_layer(AH, AL, Wt + 32768, wavecol, l15, kg, acc);

    #pragma unroll
    for (int ni = 0; ni < 2; ++ni) {
        const int col = wavecol + ni * 16 + l15;
        const float bv = g2b[col];
        float part = 0.f;
        #pragma unroll
        for (int mi = 0; mi < 4; ++mi)
            #pragma unroll
            for (int r = 0; r < 4; ++r) {
                int row = row0 + mi * 16 + rg + r;
                if (row < N) {
                    float v = acc[mi][ni][r] + bv;
                    bfused[(size_t)row * 512 + 128 + col] = v;   // Q-block scratch
                    part += v;
                }
            }
        atomicAdd(&csum[col], part);
    }
    __syncthreads();
    if (tid < 128) atomicAdd(&gsum[tid], csum[tid]);
}

// ---- fused head: in = Q-block of bfused ----
__global__ __launch_bounds__(256) void fused_head(
    const float* __restrict__ bfused, const unsigned short* __restrict__ Wt,
    const float* __restrict__ cvec, const float* __restrict__ h2b,
    const float* __restrict__ h3w, const float* __restrict__ h3b,
    float* __restrict__ out, int N)
{
    __shared__ unsigned short AH[64][LW], AL[64][LW];
    const int tid = threadIdx.x;
    const int lane = tid & 63, wid = tid >> 6;
    const int wavecol = wid * 32;
    const int l15 = lane & 15, kg = (lane >> 4) * 8, rg = (lane >> 4) * 4;
    const int row0 = blockIdx.x * 64;

    int arow[4];
    #pragma unroll
    for (int mi = 0; mi < 4; ++mi) {
        int r = row0 + mi * 16 + l15;
        arow[mi] = r < N ? r : N - 1;
    }

    f32x4 acc[4][2] = {};
    glb_layer(bfused + 128, 512, arow, Wt, wavecol, l15, kg, acc);
    epi_lds(acc, AH, AL, cvec, wavecol, l15, rg, 1);
    __syncthreads();

    #pragma unroll
    for (int mi = 0; mi < 4; ++mi)
        #pragma unroll
        for (int ni = 0; ni < 2; ++ni) acc[mi][ni] = (f32x4){0,0,0,0};
    lds_layer(AH, AL, Wt + 32768, wavecol, l15, kg, acc);
    __syncthreads();
    epi_lds(acc, AH, AL, h2b, wavecol, l15, rg, 1);
    __syncthreads();

    const int row = tid >> 2, seg = tid & 3;
    float s = 0.f;
    #pragma unroll 8
    for (int j = 0; j < 32; ++j) {
        int col = seg * 32 + j;
        float xv = __uint_as_float((unsigned int)AH[row][col] << 16)
                 + __uint_as_float((unsigned int)AL[row][col] << 16);
        s = fmaf(xv, h3w[col], s);
    }
    s += __shfl_xor(s, 1, 64);
    s += __shfl_xor(s, 2, 64);
    if (seg == 0 && row0 + row < N) out[row0 + row] = s + h3b[0];
}

// one-time: transpose+split weight units to bf16 hi/lo [m][k].
__global__ __launch_bounds__(256) void prep_weights(
    const float* __restrict__ embW, const float* __restrict__ keyW,
    const float* __restrict__ qryW, const float* __restrict__ valW,
    const float* __restrict__ skpW, const float* __restrict__ g1W,
    const float* __restrict__ g2W, const float* __restrict__ h1W,
    const float* __restrict__ h2W,
    const float* __restrict__ keyb, const float* __restrict__ qryb,
    const float* __restrict__ valb, const float* __restrict__ skpb,
    unsigned short* __restrict__ Wt, float* __restrict__ biasCat)
{
    const int u = blockIdx.x;   // 0..14
    const int t = threadIdx.x;
    __shared__ float T[128][129];

    const float* src;
    if (u < 3)       src = embW + (size_t)u * 16384;
    else if (u < 7)  { const float* p[4] = {keyW, qryW, valW, skpW}; src = p[u - 3]; }
    else if (u < 11) { const float* p[4] = {keyW, qryW, valW, skpW}; src = p[u - 7] + 16384; }
    else if (u == 11) src = g1W;
    else if (u == 12) src = g2W;
    else if (u == 13) src = h1W;
    else              src = h2W;

    #pragma unroll
    for (int i = 0; i < 64; ++i) {
        int idx = t + 256 * i;
        T[idx >> 7][idx & 127] = src[idx];
    }
    __syncthreads();

    unsigned short* dH = Wt + (size_t)u * 32768;
    unsigned short* dL = dH + 16384;
    const int m = t >> 1, kbase = (t & 1) * 64;
    for (int j = 0; j < 64; ++j) {
        int k = kbase + j;
        float a = T[k][m];
        unsigned int b = __float_as_uint(a);
        unsigned int h = b & 0xFFFF0000u;
        float r = a - __uint_as_float(h);
        dH[m * 128 + k] = (unsigned short)(h >> 16);
        dL[m * 128 + k] = (unsigned short)(__float_as_uint(r) >> 16);
    }

    if (u == 0) {
        for (int x = t; x < 1024; x += 256) {
            int L = x >> 9, c = x & 511;
            const float* bp = (c < 128) ? keyb : (c < 256) ? qryb : (c < 384) ? valb : skpb;
            biasCat[x] = bp[L * 128 + (c & 127)];
        }
    }
}

// ---------------- CSR build ----------------
__global__ void hist_kernel(const int* __restrict__ dstA, int* __restrict__ hist, int E)
{
    for (int e = blockIdx.x * blockDim.x + threadIdx.x; e < E;
         e += gridDim.x * blockDim.x)
        atomicAdd(&hist[dstA[e]], 1);
}

__global__ __launch_bounds__(256) void scan1_kernel(
    const int* __restrict__ in, int n_in,
    int* __restrict__ out, int* __restrict__ bsum, int n)
{
    __shared__ int wtot[4];
    const int t = threadIdx.x, lane = t & 63, wv = t >> 6;
    const int base = blockIdx.x * 1024 + t * 4;
    int v[4]; int sum = 0;
    #pragma unroll
    for (int j = 0; j < 4; ++j) {
        int idx = base + j;
        v[j] = (idx < n_in) ? in[idx] : 0;
        sum += v[j];
    }
    int incl = sum;
    #pragma unroll
    for (int d = 1; d < 64; d <<= 1) {
        int y = __shfl_up(incl, d, 64);
        if (lane >= d) incl += y;
    }
    if (lane == 63) wtot[wv] = incl;
    __syncthreads();
    int woff = 0;
    for (int w = 0; w < wv; ++w) woff += wtot[w];
    int run = woff + incl - sum;
    #pragma unroll
    for (int j = 0; j < 4; ++j) {
        int idx = base + j;
        if (idx < n) out[idx] = run;
        run += v[j];
    }
    if (t == 0)
        bsum[blockIdx.x] = wtot[0] + wtot[1] + wtot[2] + wtot[3];
}

__global__ void scan2_kernel(int* __restrict__ bsum, int nb)
{
    if (blockIdx.x == 0 && threadIdx.x == 0) {
        int run = 0;
        for (int i = 0; i < nb; ++i) { int t = bsum[i]; bsum[i] = run; run += t; }
    }
}

__global__ __launch_bounds__(256) void scan3_kernel(
    int* __restrict__ out, const int* __restrict__ bsum,
    int* __restrict__ cursor, int n, int n_nodes)
{
    const int base = blockIdx.x * 1024 + threadIdx.x * 4;
    const int add = bsum[blockIdx.x];
    #pragma unroll
    for (int j = 0; j < 4; ++j) {
        int idx = base + j;
        if (idx < n) {
            int vv = out[idx] + add;
            out[idx] = vv;
            if (idx < n_nodes) cursor[idx] = vv;
        }
    }
}

// fused scatter: srcp[pos] = src; eaP[pos] = ea[e] (dst-sorted, stride 24)
__global__ void scatter_ea(const int* __restrict__ srcA, const int* __restrict__ dstA,
                           const float* __restrict__ ea, int* __restrict__ cursor,
                           int* __restrict__ srcp, float* __restrict__ eaP, int E)
{
    for (int e = blockIdx.x * blockDim.x + threadIdx.x; e < E;
         e += gridDim.x * blockDim.x) {
        int d = dstA[e];
        int pos = atomicAdd(&cursor[d], 1);
        srcp[pos] = srcA[e];
        const float* s = ea + (size_t)e * 21;
        float* q = eaP + (size_t)pos * 24;
        #pragma unroll
        for (int j = 0; j < 21; ++j) q[j] = s[j];
    }
}

// ---------------- edge aggregation: wave per dst, 1-deep software pipeline ----------
// fused row: [K | Q | V | Sk]; output written into K-block (cols 0..127).
__global__ __launch_bounds__(256) void edge_agg14(
    const int* __restrict__ row_ptr, const int* __restrict__ srcp,
    const float* __restrict__ eaP,
    const float* __restrict__ We, const float* __restrict__ be,
    float* __restrict__ fused, int N)
{
    const int wv = threadIdx.x >> 6, lane = threadIdx.x & 63;
    const int d = blockIdx.x * 4 + wv;
    if (d >= N) return;
    const int c = lane * 2;

    float2 w[21];
    #pragma unroll
    for (int j = 0; j < 21; ++j)
        w[j] = *(const float2*)(We + j * DD + c);
    const float2 b2 = *(const float2*)(be + c);
    const float2 kd = *(const float2*)(fused + (size_t)d * 512 + c);
    const float2 sk = *(const float2*)(fused + (size_t)d * 512 + 384 + c);

    float ax = 0.f, ay = 0.f;
    const int i0 = __builtin_amdgcn_readfirstlane(row_ptr[d]);
    const int i1 = __builtin_amdgcn_readfirstlane(row_ptr[d + 1]);

    // prologue: load first pair's q/v
    float2 qA = {0,0}, vA = {0,0}, qB = {0,0}, vB = {0,0};
    if (i0 < i1) {
        const int iB0 = (i0 + 1 < i1) ? i0 + 1 : i0;
        const int sA = __builtin_amdgcn_readfirstlane(srcp[i0]);
        const int sB = __builtin_amdgcn_readfirstlane(srcp[iB0]);
        const float* fpA = fused + (size_t)sA * 512;
        const float* fpB = fused + (size_t)sB * 512;
        qA = *(const float2*)(fpA + 128 + c);
        vA = *(const float2*)(fpA + 256 + c);
        qB = *(const float2*)(fpB + 128 + c);
        vB = *(const float2*)(fpB + 256 + c);
    }

    for (int i = i0; i < i1; i += 2) {
        const float wgtB = (i + 1 < i1) ? 1.f : 0.f;
        const int iBc = (i + 1 < i1) ? i + 1 : i;

        // snapshot current pair's gathers (loaded last iteration)
        const float2 cqA = qA, cvA = vA, cqB = qB, cvB = vB;

        // prefetch next pair's q/v (overlaps with this iteration's compute)
        const int inx = i + 2;
        if (inx < i1) {
            const int inB = (inx + 1 < i1) ? inx + 1 : inx;
            const int sA = __builtin_amdgcn_readfirstlane(srcp[inx]);
            const int sB = __builtin_amdgcn_readfirstlane(srcp[inB]);
            const float* fpA = fused + (size_t)sA * 512;
            const float* fpB = fused + (size_t)sB * 512;
            qA = *(const float2*)(fpA + 128 + c);
            vA = *(const float2*)(fpA + 256 + c);
            qB = *(const float2*)(fpB + 128 + c);
            vB = *(const float2*)(fpB + 256 + c);
        }

        // ea rows: loop-affine uniform addresses -> scalar loads
        const float* eA = eaP + (size_t)i * 24;
        const float* eB = eaP + (size_t)iBc * 24;
        float aA[21], aB[21];
        #pragma unroll
        for (int j = 0; j < 21; ++j) { aA[j] = eA[j]; aB[j] = eB[j]; }

        float pxA[4] = {0,0,0,0}, pyA[4] = {0,0,0,0};
        float pxB[4] = {0,0,0,0}, pyB[4] = {0,0,0,0};
        #pragma unroll
        for (int j = 0; j < 21; ++j) {
            int s = j & 3;
            pxA[s] = fmaf(aA[j], w[j].x, pxA[s]);
            pyA[s] = fmaf(aA[j], w[j].y, pyA[s]);
            pxB[s] = fmaf(aB[j], w[j].x, pxB[s]);
            pyB[s] = fmaf(aB[j], w[j].y, pyB[s]);
        }
        float exA = (pxA[0] + pxA[1]) + (pxA[2] + pxA[3]) + b2.x;
        float eyA = (pyA[0] + pyA[1]) + (pyA[2] + pyA[3]) + b2.y;
        float exB = (pxB[0] + pxB[1]) + (pxB[2] + pxB[3]) + b2.x;
        float eyB = (pyB[0] + pyB[1]) + (pyB[2] + pyB[3]) + b2.y;

        float gxA = fsig(kd.x + cqA.x + exA);
        float gyA = fsig(kd.y + cqA.y + eyA);
        float gxB = wgtB * fsig(kd.x + cqB.x + exB);
        float gyB = wgtB * fsig(kd.y + cqB.y + eyB);

        ax = fmaf(gxA, cvA.x, ax);
        ay = fmaf(gyA, cvA.y, ay);
        ax = fmaf(gxB, cvB.x, ax);
        ay = fmaf(gyB, cvB.y, ay);
    }

    float* xr = fused + (size_t)d * 512;
    xr[c]     = fmaxf(ax + sk.x, 0.f);
    xr[c + 1] = fmaxf(ay + sk.y, 0.f);
}

__global__ void cvec_kernel(const float* __restrict__ gsum, const float* __restrict__ h1W,
                            const float* __restrict__ h1b, float* __restrict__ cvec, float invN)
{
    const int m = threadIdx.x;
    float acc = h1b[m];
    for (int k = 0; k < 128; ++k)
        acc = fmaf(gsum[k] * invN, h1W[(size_t)(128 + k) * DD + m], acc);
    cvec[m] = acc;
}

extern "C" void kernel_launch(void* const* d_in, const int* in_sizes, int n_in,
                              void* d_out, int out_size, void* d_ws, size_t ws_size,
                              hipStream_t stream)
{
    const float* G    = (const float*)d_in[0];
    const int*   ei   = (const int*)  d_in[1];
    const float* ea   = (const float*)d_in[2];
    const float* embW = (const float*)d_in[3];
    const float* embb = (const float*)d_in[4];
    const float* keyW = (const float*)d_in[5];
    const float* keyb = (const float*)d_in[6];
    const float* qryW = (const float*)d_in[7];
    const float* qryb = (const float*)d_in[8];
    const float* valW = (const float*)d_in[9];
    const float* valb = (const float*)d_in[10];
    const float* skpW = (const float*)d_in[11];
    const float* skpb = (const float*)d_in[12];
    const float* edgW = (const float*)d_in[13];
    const float* edgb = (const float*)d_in[14];
    const float* g1W  = (const float*)d_in[15];
    const float* g1b  = (const float*)d_in[16];
    const float* g2W  = (const float*)d_in[17];
    const float* g2b  = (const float*)d_in[18];
    const float* h1W  = (const float*)d_in[19];
    const float* h1b  = (const float*)d_in[20];
    const float* h2W  = (const float*)d_in[21];
    const float* h2b  = (const float*)d_in[22];
    const float* h3W  = (const float*)d_in[23];
    const float* h3b  = (const float*)d_in[24];

    const int N = in_sizes[0] / DD;    // 100000
    const int E = in_sizes[2] / 21;    // 1000000
    const int* srcA = ei;
    const int* dstA = ei + E;

    float* bfused = (float*)d_ws;                        // [N][512]
    float* gsum   = bfused + (size_t)N * 512;            // 128
    float* cvec   = gsum + DD;                           // 128
    float* biasCat= cvec + DD;                           // 1024
    unsigned short* Wt = (unsigned short*)(biasCat + 1024);  // 15*32768 ushorts
    int* hist = (int*)((char*)Wt + (size_t)15 * 32768 * 2);  // N
    int* row  = hist + N;              // N+1
    int* cur  = row + N + 1;           // N
    int* bsum = cur + N;               // 128
    int* srcp = bsum + 128;            // E
    float* eaP = (float*)(srcp + E);   // E*24

    const int fgrid   = (N + 63) / 64;
    const int aggGrid = (N + 3) / 4;
    const int nScan = N + 1;
    const int nb = (nScan + 1023) / 1024;

    // ---- weight prep + CSR build (scatter fused with ea permute) ----
    prep_weights<<<15, 256, 0, stream>>>(embW, keyW, qryW, valW, skpW,
                                         g1W, g2W, h1W, h2W,
                                         keyb, qryb, valb, skpb, Wt, biasCat);
    hipMemsetAsync(hist, 0, (size_t)N * sizeof(int), stream);
    hipMemsetAsync(gsum, 0, DD * sizeof(float), stream);
    hist_kernel<<<1024, 256, 0, stream>>>(dstA, hist, E);
    scan1_kernel<<<nb, 256, 0, stream>>>(hist, N, row, bsum, nScan);
    scan2_kernel<<<1, 64, 0, stream>>>(bsum, nb);
    scan3_kernel<<<nb, 256, 0, stream>>>(row, bsum, cur, nScan, N);
    scatter_ea<<<1024, 256, 0, stream>>>(srcA, dstA, ea, cur, srcp, eaP, E);

    #define UNIT(u) (Wt + (size_t)(u) * 32768)

    // ---- emb MLP + kqvs layer0 fused: G -> bfused ----
    fused_emb3q<<<fgrid, 256, 0, stream>>>(G, Wt, embb, biasCat, bfused, N);

    // ---- conv layer 0 edges: bfused -> K-block of bfused ----
    edge_agg14<<<aggGrid, 256, 0, stream>>>(row, srcp, eaP,
                                            edgW + 0, edgb + 0, bfused, N);

    // ---- conv layer 1: kqvs (K-block in, full rows out); edges -> K-block ----
    fused_kqvs<<<fgrid, 256, 0, stream>>>(bfused, UNIT(7), biasCat + 512, N);
    edge_agg14<<<aggGrid, 256, 0, stream>>>(row, srcp, eaP,
                                            edgW + 21*DD, edgb + DD, bfused, N);

    // ---- g1+g2+colsum fused: K-block -> Q-block, gsum ----
    fused_g12<<<fgrid, 256, 0, stream>>>(bfused, UNIT(11), g1b, g2b, gsum, N);

    // ---- cvec = h1b + (gmean @ h1W[D:]) ----
    cvec_kernel<<<1, DD, 0, stream>>>(gsum, h1W, h1b, cvec, 1.0f / (float)N);

    // ---- head fused: Q-block -> out ----
    fused_head<<<fgrid, 256, 0, stream>>>(bfused, UNIT(13), cvec, h2b, h3W, h3b,
                                          (float*)d_out, N);
}